// Round 9
// baseline (284.389 us; speedup 1.0000x reference)
//
#include <hip/hip_runtime.h>

// HyperbolicAttention: N=100000 nodes, C=128, H=8 heads, D=16, E=640000 edges.
// Round 9: persistent pipelined GEMM blocks (W staged once in LDS; per tile:
//          convert-current / prefetch-next / MFMA), XCD-co-located QKV slices,
//          CSR-ordered scores+gather with 2-deep prefetch.

#define TPB 256

typedef __attribute__((ext_vector_type(8))) short short8;
typedef __attribute__((ext_vector_type(4))) short short4v;
typedef __attribute__((ext_vector_type(4))) float f32x4;

// fp32 -> bf16 round-to-nearest-even
__device__ __forceinline__ short f2bf(float f) {
    unsigned u = __float_as_uint(f);
    u += 0x7fffu + ((u >> 16) & 1u);
    return (short)(u >> 16);
}
// bf16 -> fp32
__device__ __forceinline__ float bf2f(short s) {
    return __uint_as_float(((unsigned)(unsigned short)s) << 16);
}
__device__ __forceinline__ short8 cvt8(float4 a, float4 b) {
    short8 r;
    r[0]=f2bf(a.x); r[1]=f2bf(a.y); r[2]=f2bf(a.z); r[3]=f2bf(a.w);
    r[4]=f2bf(b.x); r[5]=f2bf(b.y); r[6]=f2bf(b.z); r[7]=f2bf(b.w);
    return r;
}

// ---------------------------------------------------------------------------
// Convert the four 128x128 fp32 weight matrices to bf16 (row-major, packed).
// ---------------------------------------------------------------------------
__global__ void wconv_kernel(const float* __restrict__ W0, const float* __restrict__ W1,
                             const float* __restrict__ W2, const float* __restrict__ W3,
                             short* __restrict__ out)
{
    int i = blockIdx.x * TPB + threadIdx.x;   // 0..65535
    if (i >= 65536) return;
    const float* W = (i < 16384) ? W0 : (i < 32768) ? W1 : (i < 49152) ? W2 : W3;
    out[i] = f2bf(W[i & 16383]);
}

// ---------------------------------------------------------------------------
// Persistent GEMM body: Y = X @ W^T + b over tiles x = xstart, +xstride, ...
// W staged once in LDS (frag-major). Per tile iteration:
//   convert current raw X regs -> bf16 frags, issue next tile's loads,
//   MFMA burst (swapped operand), vectorized store.
// Lane holds x-row = l15, 4 consecutive output cols (n*16+lh*4..+3).
// ---------------------------------------------------------------------------
template<bool IN_BF16, bool OUT_BF16>
__device__ __forceinline__ void gemm_body_pers(
    const void* __restrict__ Xv, int nrows, int nxblk, int xstart, int xstride,
    const short* __restrict__ Wb, const float* __restrict__ bias,
    void* __restrict__ Yv)
{
    __shared__ short lw[16384];   // 32 KiB W, frag-major
    const int tid = threadIdx.x;

    #pragma unroll
    for (int r = 0; r < 8; ++r) {
        int c = r * 256 + tid;              // chunk id 0..2047
        int fragid = c >> 6, ln = c & 63;
        int n = fragid >> 2, kc = fragid & 3;
        *(short8*)&lw[c * 8] =
            *(const short8*)&Wb[(n*16 + (ln & 15))*128 + kc*32 + (ln >> 4)*8];
    }
    __syncthreads();

    const int wid = tid >> 6;
    const int lane = tid & 63;
    const int l15 = lane & 15;
    const int lh  = lane >> 4;

    // Raw staging registers for one tile.
    float4 xa[4][2], xb[4][2];   // fp32 input path
    short8 xr[4][2];             // bf16 input path

    auto loadx = [&](int x) {
        int rb = x * 128 + wid * 32;
        int r0 = rb + l15, r1 = r0 + 16;
        bool v0 = r0 < nrows, v1 = r1 < nrows;
        if (IN_BF16) {
            const short* Xb = (const short*)Xv;
            #pragma unroll
            for (int kc = 0; kc < 4; ++kc) {
                xr[kc][0] = v0 ? *(const short8*)&Xb[(size_t)r0*128 + kc*32 + lh*8]
                               : (short8)(short)0;
                xr[kc][1] = v1 ? *(const short8*)&Xb[(size_t)r1*128 + kc*32 + lh*8]
                               : (short8)(short)0;
            }
        } else {
            const float* Xf = (const float*)Xv;
            const float4* P0 = (const float4*)(Xf + (size_t)r0 * 128);
            const float4* P1 = (const float4*)(Xf + (size_t)r1 * 128);
            float4 z4 = make_float4(0.f, 0.f, 0.f, 0.f);
            #pragma unroll
            for (int kc = 0; kc < 4; ++kc) {
                xa[kc][0] = v0 ? P0[kc*8 + lh*2]     : z4;
                xb[kc][0] = v0 ? P0[kc*8 + lh*2 + 1] : z4;
                xa[kc][1] = v1 ? P1[kc*8 + lh*2]     : z4;
                xb[kc][1] = v1 ? P1[kc*8 + lh*2 + 1] : z4;
            }
        }
    };

    if (xstart < nxblk) loadx(xstart);

    for (int x = xstart; x < nxblk; x += xstride) {
        // Consume raw regs -> bf16 fragments for this tile.
        short8 xf[4][2];
        if (IN_BF16) {
            #pragma unroll
            for (int kc = 0; kc < 4; ++kc) {
                xf[kc][0] = xr[kc][0];
                xf[kc][1] = xr[kc][1];
            }
        } else {
            #pragma unroll
            for (int kc = 0; kc < 4; ++kc) {
                xf[kc][0] = cvt8(xa[kc][0], xb[kc][0]);
                xf[kc][1] = cvt8(xa[kc][1], xb[kc][1]);
            }
        }

        // Prefetch next tile: loads in flight during MFMA + epilogue.
        if (x + xstride < nxblk) loadx(x + xstride);

        f32x4 acc[8][2];
        #pragma unroll
        for (int n = 0; n < 8; ++n) { acc[n][0] = (f32x4)0.f; acc[n][1] = (f32x4)0.f; }

        #pragma unroll
        for (int kc = 0; kc < 4; ++kc) {
            short8 wf[8];
            #pragma unroll
            for (int n = 0; n < 8; ++n)
                wf[n] = *(const short8*)&lw[((n*4 + kc)*64 + lane) * 8];
            #pragma unroll
            for (int n = 0; n < 8; ++n) {
                acc[n][0] = __builtin_amdgcn_mfma_f32_16x16x32_bf16(wf[n], xf[kc][0], acc[n][0], 0, 0, 0);
                acc[n][1] = __builtin_amdgcn_mfma_f32_16x16x32_bf16(wf[n], xf[kc][1], acc[n][1], 0, 0, 0);
            }
        }

        // Epilogue for this tile.
        const int rowbase = x * 128 + wid * 32;
        #pragma unroll
        for (int g = 0; g < 2; ++g) {
            int row = rowbase + g*16 + l15;
            if (row >= nrows) continue;
            #pragma unroll
            for (int n = 0; n < 8; ++n) {
                float4 b4 = *(const float4*)&bias[n*16 + lh*4];
                float y0 = acc[n][g][0] + b4.x;
                float y1 = acc[n][g][1] + b4.y;
                float y2 = acc[n][g][2] + b4.z;
                float y3 = acc[n][g][3] + b4.w;
                if (OUT_BF16) {
                    short4v s; s[0]=f2bf(y0); s[1]=f2bf(y1); s[2]=f2bf(y2); s[3]=f2bf(y3);
                    *(short4v*)&((short*)Yv)[(size_t)row * 128 + n*16 + lh*4] = s;
                } else {
                    *(float4*)&((float*)Yv)[(size_t)row * 128 + n*16 + lh*4] =
                        make_float4(y0, y1, y2, y3);
                }
            }
        }
    }
}

// Fused QKV, persistent + XCD co-located: w = b>>8, xstart = b&255, stride 256.
// Blocks c, c+256, c+512 share b%8 (same XCD) and identical tile sequences.
__global__ __launch_bounds__(256) void gemm_qkv_kernel(
    const float* __restrict__ X, int nrows, int nxblk,
    const short* __restrict__ WB,
    const float* __restrict__ bq, const float* __restrict__ bk,
    const float* __restrict__ bv,
    short* __restrict__ Yb, size_t slice)
{
    int b = blockIdx.x;
    int w = b >> 8;
    int xstart = b & 255;
    const float* bias = (w == 0) ? bq : (w == 1) ? bk : bv;
    gemm_body_pers<false, true>(X, nrows, nxblk, xstart, 256,
                                WB + w * 16384, bias, Yb + (size_t)w * slice);
}

// Output projection, persistent: bf16 in, fp32 out.
__global__ __launch_bounds__(256) void gemm_out_kernel(
    const short* __restrict__ Xb, int nrows, int nxblk,
    const short* __restrict__ Wb, const float* __restrict__ bias,
    float* __restrict__ Y)
{
    gemm_body_pers<true, false>(Xb, nrows, nxblk, blockIdx.x, 512, Wb, bias, Y);
}

// ---------------------------------------------------------------------------
// edge_index may arrive as int64 (reference) or int32. Detect on device.
// ---------------------------------------------------------------------------
__global__ void detect_i64_kernel(const int* __restrict__ raw, int* __restrict__ flag)
{
    if (blockIdx.x == 0 && threadIdx.x == 0) {
        int odd_nonzero = 0;
        for (int i = 0; i < 128; ++i)
            if (raw[2 * i + 1] != 0) odd_nonzero = 1;
        *flag = odd_nonzero ? 0 : 1;  // 1 => int64 layout
    }
}

// Convert to int32; simultaneously histogram destination rows (i < E).
__global__ void conv_hist_kernel(const void* __restrict__ raw, int E,
                                 const int* __restrict__ flag,
                                 int* __restrict__ out, int* __restrict__ deg)
{
    int i = blockIdx.x * TPB + threadIdx.x;
    if (i >= 2 * E) return;
    int v;
    if (*flag) v = (int)((const long long*)raw)[i];
    else       v = ((const int*)raw)[i];
    out[i] = v;
    if (i < E) atomicAdd(&deg[v], 1);
}

// ---------------------------------------------------------------------------
// CSR scan: block-local exclusive scan, block-sum scan, add-back (also
// initializes cursor = rowstart).
// ---------------------------------------------------------------------------
__global__ void scan1_kernel(const int* __restrict__ deg, int n,
                             int* __restrict__ rowstart, int* __restrict__ bsum)
{
    __shared__ int sm[TPB];
    int t = threadIdx.x;
    int gid = blockIdx.x * TPB + t;
    int v = (gid < n) ? deg[gid] : 0;
    sm[t] = v;
    __syncthreads();
    for (int off = 1; off < TPB; off <<= 1) {
        int x = (t >= off) ? sm[t - off] : 0;
        __syncthreads();
        sm[t] += x;
        __syncthreads();
    }
    if (gid < n) rowstart[gid] = sm[t] - v;
    if (t == TPB - 1) bsum[blockIdx.x] = sm[t];
}

__global__ void scan2_kernel(int* __restrict__ bsum, int nb)
{
    __shared__ int sm[512];
    int t = threadIdx.x;
    int v = (t < nb) ? bsum[t] : 0;
    sm[t] = v;
    __syncthreads();
    for (int off = 1; off < 512; off <<= 1) {
        int x = (t >= off) ? sm[t - off] : 0;
        __syncthreads();
        sm[t] += x;
        __syncthreads();
    }
    if (t < nb) bsum[t] = sm[t] - v;
}

__global__ void scan3_kernel(int* __restrict__ rowstart, int* __restrict__ cursor,
                             int n, int E, const int* __restrict__ bsum)
{
    int gid = blockIdx.x * TPB + threadIdx.x;
    if (gid < n) {
        int v = rowstart[gid] + bsum[blockIdx.x];
        rowstart[gid] = v;
        cursor[gid] = v;
    }
    if (gid == 0) rowstart[n] = E;
}

// Bin edges by destination: ecol[p] = col of edge, p in the dest's segment.
__global__ void fill_kernel(const int* __restrict__ ei, int E,
                            int* __restrict__ cursor, int* __restrict__ ecol)
{
    int e = blockIdx.x * TPB + threadIdx.x;
    if (e >= E) return;
    int pos = atomicAdd(&cursor[ei[e]], 1);
    ecol[pos] = ei[E + e];
}

// ---------------------------------------------------------------------------
// CSR-ordered scores + fused online softmax partials, 2-deep prefetch.
// thread = (node, h): Q slice in regs; K rows shared by the node's 8 lanes;
// S written sequentially at [p*8+h].
// ---------------------------------------------------------------------------
__global__ __launch_bounds__(256) void csr_score_stats_kernel(
    const short* __restrict__ Qb, const short* __restrict__ Kb,
    const int* __restrict__ ecol, const int* __restrict__ rowstart, int N,
    float* __restrict__ S, float* __restrict__ mpart, float* __restrict__ zpart)
{
    int t = threadIdx.x;
    int idx = blockIdx.x * TPB + t;
    float m = -3.0e38f, z = 0.f;
    if (idx < N * 8) {
        int node = idx >> 3, h = idx & 7;
        const short8* q8 = (const short8*)(Qb + (size_t)node * 128 + h * 16);
        short8 q0 = q8[0], q1 = q8[1];
        int p0 = rowstart[node], p1 = rowstart[node + 1];
        if (p0 < p1) {
            const short8* kc = (const short8*)(Kb + (size_t)ecol[p0] * 128 + h * 16);
            short8 k0 = kc[0], k1 = kc[1];
            for (int p = p0; p < p1; ++p) {
                short8 k0n = k0, k1n = k1;
                if (p + 1 < p1) {
                    const short8* kn = (const short8*)(Kb + (size_t)ecol[p+1] * 128 + h * 16);
                    k0n = kn[0]; k1n = kn[1];
                }
                float dot = 0.f;
                #pragma unroll
                for (int i = 0; i < 8; ++i) {
                    dot += bf2f(q0[i]) * bf2f(k0[i]);
                    dot += bf2f(q1[i]) * bf2f(k1[i]);
                }
                float s = dot * 0.25f;  // 1/sqrt(16)
                S[(size_t)p * 8 + h] = s;
                float M = fmaxf(m, s);
                z = z * __expf(m - M) + __expf(s - M);
                m = M;
                k0 = k0n; k1 = k1n;
            }
        }
    }
    __shared__ float sm[TPB], sz[TPB];
    sm[t] = m; sz[t] = z;
    __syncthreads();
    for (int off = 128; off >= 8; off >>= 1) {
        if (t < off) {
            float m2 = sm[t + off], z2 = sz[t + off];
            float M = fmaxf(sm[t], m2);
            sz[t] = sz[t] * __expf(sm[t] - M) + z2 * __expf(m2 - M);
            sm[t] = M;
        }
        __syncthreads();
    }
    if (t < 8) {
        mpart[blockIdx.x * 8 + t] = sm[t];
        zpart[blockIdx.x * 8 + t] = sz[t];
    }
}

// One block: combine nb per-block partials -> MZ[h] (max), MZ[8+h] (Z).
__global__ void stats_reduce_kernel(const float* __restrict__ mpart,
                                    const float* __restrict__ zpart,
                                    int nb, float* __restrict__ MZ)
{
    int t = threadIdx.x;
    int h = t & 7, chunk = t >> 3;   // 32 chunks
    float m = -3.0e38f, z = 0.f;
    for (int i = chunk; i < nb; i += 32) {
        float m2 = mpart[i * 8 + h], z2 = zpart[i * 8 + h];
        float M = fmaxf(m, m2);
        z = z * __expf(m - M) + z2 * __expf(m2 - M);
        m = M;
    }
    __shared__ float sm[TPB], sz[TPB];
    sm[t] = m; sz[t] = z;
    __syncthreads();
    for (int off = 128; off >= 8; off >>= 1) {
        if (t < off) {
            float m2 = sm[t + off], z2 = sz[t + off];
            float M = fmaxf(sm[t], m2);
            sz[t] = sz[t] * __expf(sm[t] - M) + z2 * __expf(m2 - M);
            sm[t] = M;
        }
        __syncthreads();
    }
    if (t < 8) { MZ[t] = sm[t]; MZ[8 + t] = sz[t]; }
}

// ---------------------------------------------------------------------------
// Gather segment-sum, fused exp/normalize, 2-deep prefetch.
// thread = (node, head); S sequential; V rows shared by the node's 8 lanes.
// ---------------------------------------------------------------------------
__global__ __launch_bounds__(256) void gather_kernel(
    const float* __restrict__ S, const short* __restrict__ Vb,
    const int* __restrict__ ecol,
    const int* __restrict__ rowstart,
    const float* __restrict__ MZ, int N,
    short* __restrict__ outb)
{
    int idx = blockIdx.x * TPB + threadIdx.x;
    if (idx >= N * 8) return;
    int node = idx >> 3, h = idx & 7;
    float M = MZ[h];
    float invZ = 1.0f / MZ[8 + h];
    int p0 = rowstart[node], p1 = rowstart[node + 1];

    float a[16];
    #pragma unroll
    for (int i = 0; i < 16; ++i) a[i] = 0.f;

    if (p0 < p1) {
        const short8* vc = (const short8*)(Vb + (size_t)ecol[p0] * 128 + h * 16);
        short8 v0 = vc[0], v1 = vc[1];
        float sc = S[(size_t)p0 * 8 + h];
        for (int p = p0; p < p1; ++p) {
            short8 v0n = v0, v1n = v1;
            float sn = sc;
            if (p + 1 < p1) {
                const short8* vn = (const short8*)(Vb + (size_t)ecol[p+1] * 128 + h * 16);
                v0n = vn[0]; v1n = vn[1];
                sn = S[(size_t)(p+1) * 8 + h];
            }
            float w = __expf(sc - M) * invZ;
            #pragma unroll
            for (int i = 0; i < 8; ++i) {
                a[i]     += w * bf2f(v0[i]);
                a[8 + i] += w * bf2f(v1[i]);
            }
            v0 = v0n; v1 = v1n; sc = sn;
        }
    }
    short8 o0, o1;
    #pragma unroll
    for (int i = 0; i < 8; ++i) { o0[i] = f2bf(a[i]); o1[i] = f2bf(a[8 + i]); }
    short8* ob = (short8*)(outb + (size_t)node * 128 + h * 16);
    ob[0] = o0; ob[1] = o1;
}

// ---------------------------------------------------------------------------
extern "C" void kernel_launch(void* const* d_in, const int* in_sizes, int n_in,
                              void* d_out, int out_size, void* d_ws, size_t ws_size,
                              hipStream_t stream)
{
    const float* feat = (const float*)d_in[0];
    const void*  eraw = d_in[1];
    const float* Wq = (const float*)d_in[2];
    const float* bq = (const float*)d_in[3];
    const float* Wk = (const float*)d_in[4];
    const float* bk = (const float*)d_in[5];
    const float* Wv = (const float*)d_in[6];
    const float* bv = (const float*)d_in[7];
    const float* Wo = (const float*)d_in[8];
    const float* bo = (const float*)d_in[9];

    const int N = in_sizes[0] / 128;
    const int E = in_sizes[1] / 2;
    const size_t NC = (size_t)N * 128;
    const int EH = E * 8;
    const int gbN = (N * 8 + TPB - 1) / TPB;   // node-head grid (scores/gather)

    // Workspace layout
    short* Qb   = (short*)d_ws;            // [N][128] bf16 (Q,K,V contiguous)
    short* Kb   = Qb + NC;
    short* Vb   = Kb + NC;
    short* ACCb = Vb + NC;                 // [N][128] bf16
    float* S    = (float*)(ACCb + NC);     // [E*8] scores, CSR order
    int*   EI   = (int*)(S + EH);          // int32 indices, 2*E
    short* WB   = (short*)(EI + 2 * E);    // 4 x 16384 bf16 weights
    float* mpart = (float*)(WB + 65536);   // [gbN][8]
    float* zpart = mpart + (size_t)gbN * 8;
    float* MZ    = zpart + (size_t)gbN * 8; // 16: M[8], Z[8]
    int*   flag  = (int*)(MZ + 16);
    int* deg      = flag + 16;             // N
    int* rowstart = deg + N;               // N+1
    int* cursor   = rowstart + N + 1;      // N
    int* bsum     = cursor + N;            // 512
    int* ecol     = bsum + 512;            // E (binned cols)

    const int nbS = (N + TPB - 1) / TPB;
    const int ebE = (E + TPB - 1) / TPB;

    // --- CSR build (independent of GEMMs) ---
    hipMemsetAsync(deg, 0, (size_t)N * sizeof(int), stream);
    detect_i64_kernel<<<1, 64, 0, stream>>>((const int*)eraw, flag);
    conv_hist_kernel<<<(2 * E + TPB - 1) / TPB, TPB, 0, stream>>>(eraw, E, flag, EI, deg);
    scan1_kernel<<<nbS, TPB, 0, stream>>>(deg, N, rowstart, bsum);
    scan2_kernel<<<1, 512, 0, stream>>>(bsum, nbS);
    scan3_kernel<<<nbS, TPB, 0, stream>>>(rowstart, cursor, N, E, bsum);
    fill_kernel<<<ebE, TPB, 0, stream>>>(EI, E, cursor, ecol);

    // --- Projections ---
    wconv_kernel<<<256, TPB, 0, stream>>>(Wq, Wk, Wv, Wo, WB);
    const int gb = (N + 127) / 128;                 // X tiles (782)
    gemm_qkv_kernel<<<768, TPB, 0, stream>>>(feat, N, gb, WB, bq, bk, bv, Qb, NC);

    // --- Scores + softmax stats (CSR order) ---
    csr_score_stats_kernel<<<gbN, TPB, 0, stream>>>(Qb, Kb, ecol, rowstart, N,
                                                    S, mpart, zpart);
    stats_reduce_kernel<<<1, TPB, 0, stream>>>(mpart, zpart, gbN, MZ);

    // --- Gather segment-sum with fused exp/normalize -> bf16 ACC ---
    gather_kernel<<<gbN, TPB, 0, stream>>>(S, Vb, ecol, rowstart, MZ, N, ACCb);

    // --- Output projection (bf16 in, fp32 out) ---
    gemm_out_kernel<<<512, TPB, 0, stream>>>(ACCb, N, gb, WB + 3 * 16384, bo, (float*)d_out);
}